// Round 8
// baseline (1731.903 us; speedup 1.0000x reference)
//
#include <hip/hip_runtime.h>
#include <stdint.h>

#define BB 128
#define SS 2048
#define TT 128
#define NSEG 32
#define SEGK 64
#define CHK 32               // e-chunk rows / hist-stage rows

#define TRP 129              // trans row stride in LDS (129 % 32 == 1)
#define SPITCH 160           // state buffer stride (dwords)
#define PI(i) ((i) + (((i) >> 4) << 2))   // pad 4 dwords per 16

typedef float f32x4 __attribute__((ext_vector_type(4)));

// raw barrier: drain LDS ops only
#define BAR() asm volatile("s_waitcnt lgkmcnt(0)\n\ts_barrier" ::: "memory")
#define PIN(x) asm volatile("" : "+v"(x))

template <int CTRL>
__device__ __forceinline__ float dppf(float x) {
    return __int_as_float(__builtin_amdgcn_update_dpp(0, __float_as_int(x), CTRL, 0xF, 0xF, true));
}
template <int CTRL>
__device__ __forceinline__ int dppi(int x) {
    return __builtin_amdgcn_update_dpp(0, x, CTRL, 0xF, 0xF, true);
}
// 0xB1 = quad_perm xor1, 0x4E = quad_perm xor2, 0x141 = row_half_mirror (xor7 in 8-group)

__device__ __forceinline__ f32x4 fmax4(f32x4 a, f32x4 b) {
    f32x4 r;
    r.x = fmaxf(a.x, b.x); r.y = fmaxf(a.y, b.y);
    r.z = fmaxf(a.z, b.z); r.w = fmaxf(a.w, b.w);
    return r;
}

// load chunk rows [s0, s0+CHK) into 4 regs (clamped to array end)
#define ECHUNK_LOAD(s0)                                                       \
{                                                                             \
    _Pragma("unroll")                                                         \
    for (int p = 0; p < 4; ++p) {                                             \
        int f = p * 1024 + tid * 4;                                           \
        int gf = (s0) * TT + f;                                               \
        int mx = (SS - 1) * TT + (f & (TT - 1));                              \
        gf = (gf < mx) ? gf : mx;                                             \
        ec[p] = *(const f32x4*)(logit + lbase + gf);                          \
    }                                                                         \
}
#define ECHUNK_STORE(dstbuf)                                                  \
{                                                                             \
    _Pragma("unroll")                                                         \
    for (int p = 0; p < 4; ++p)                                               \
        *(f32x4*)((dstbuf) + p * 1024 + tid * 4) = ec[p];                     \
}

// one viterbi step: R5 mapping (4 cols x 16 i per lane), NO VMEM, reg argmax
#define VSTEP5(slot, CURP)                                                    \
{                                                                             \
    const int cur_ = (CURP), nxt_ = 1 - cur_;                                 \
    const f32x4 e4_ = *(const f32x4*)(ecur + (slot) * TT + j0);               \
    const f32x4* sq_ = (const f32x4*)(stateLDS + cur_ * SPITCH + 20 * ig);    \
    f32x4 s0_ = sq_[0], s1_ = sq_[1], s2_ = sq_[2], s3_ = sq_[3];             \
    float va_[4];                                                             \
    int   pidx_[4];                                                           \
    _Pragma("unroll")                                                         \
    for (int q = 0; q < 4; ++q) {                                             \
        f32x4 P0 = s0_ + tj[q][0];                                            \
        f32x4 P1 = s1_ + tj[q][1];                                            \
        f32x4 P2 = s2_ + tj[q][2];                                            \
        f32x4 P3 = s3_ + tj[q][3];                                            \
        f32x4 m4 = fmax4(fmax4(P0, P1), fmax4(P2, P3));                       \
        float M_ = fmaxf(fmaxf(m4.x, m4.y), fmaxf(m4.z, m4.w));               \
        M_ = fmaxf(M_, dppf<0xB1>(M_));                                       \
        M_ = fmaxf(M_, dppf<0x4E>(M_));                                       \
        M_ = fmaxf(M_, dppf<0x141>(M_));                                      \
        const float e_ = (q == 0) ? e4_.x : (q == 1) ? e4_.y                  \
                        : (q == 2) ? e4_.z : e4_.w;                           \
        const float v_ = M_ + e_;   /* exact reference max value */           \
        int idx_ = 0x7fffffff;                                                \
        {                                                                     \
            f32x4 qv;                                                         \
            qv = P3 + e_;                                                     \
            idx_ = (qv.w == v_) ? (ibase + 15) : idx_;                        \
            idx_ = (qv.z == v_) ? (ibase + 14) : idx_;                        \
            idx_ = (qv.y == v_) ? (ibase + 13) : idx_;                        \
            idx_ = (qv.x == v_) ? (ibase + 12) : idx_;                        \
            qv = P2 + e_;                                                     \
            idx_ = (qv.w == v_) ? (ibase + 11) : idx_;                        \
            idx_ = (qv.z == v_) ? (ibase + 10) : idx_;                        \
            idx_ = (qv.y == v_) ? (ibase + 9) : idx_;                         \
            idx_ = (qv.x == v_) ? (ibase + 8) : idx_;                         \
            qv = P1 + e_;                                                     \
            idx_ = (qv.w == v_) ? (ibase + 7) : idx_;                         \
            idx_ = (qv.z == v_) ? (ibase + 6) : idx_;                         \
            idx_ = (qv.y == v_) ? (ibase + 5) : idx_;                         \
            idx_ = (qv.x == v_) ? (ibase + 4) : idx_;                         \
            qv = P0 + e_;                                                     \
            idx_ = (qv.w == v_) ? (ibase + 3) : idx_;                         \
            idx_ = (qv.z == v_) ? (ibase + 2) : idx_;                         \
            idx_ = (qv.y == v_) ? (ibase + 1) : idx_;                         \
            idx_ = (qv.x == v_) ? (ibase + 0) : idx_;                         \
        }                                                                     \
        int o_;                                                               \
        o_ = dppi<0xB1>(idx_);  idx_ = (o_ < idx_) ? o_ : idx_;               \
        o_ = dppi<0x4E>(idx_);  idx_ = (o_ < idx_) ? o_ : idx_;               \
        o_ = dppi<0x141>(idx_); idx_ = (o_ < idx_) ? o_ : idx_;               \
        va_[q] = v_;                                                          \
        pidx_[q] = idx_;                                                      \
    }                                                                         \
    if (ig == 0) {                                                            \
        f32x4 vv_ = {va_[0], va_[1], va_[2], va_[3]};                         \
        *(f32x4*)(stateLDS + nxt_ * SPITCH + PI(j0)) = vv_;                   \
    }                                                                         \
    if (ig == 1) {                                                            \
        uint32_t pk_ = (uint32_t)pidx_[0] | ((uint32_t)pidx_[1] << 8) |       \
                       ((uint32_t)pidx_[2] << 16) | ((uint32_t)pidx_[3] << 24); \
        *(uint32_t*)(hsLDS + (slot) * TT + j0) = pk_;                         \
    }                                                                         \
    BAR();                                                                    \
}

// one forward step: R5 mapping, NO VMEM
#define FSTEP5(slot, CURP)                                                    \
{                                                                             \
    const int cur_ = (CURP), nxt_ = 1 - cur_;                                 \
    const int tt_ = tc + (slot);                                              \
    const float Rcons_ = ringLDS[(tt_ - 3) & 3];                              \
    const float Rpub_  = ringLDS[(tt_ - 2) & 3];                              \
    const f32x4 e4_ = *(const f32x4*)(ecur + (slot) * TT + j0);               \
    const f32x4* aq_ = (const f32x4*)(stateLDS + cur_ * SPITCH + 20 * ig);    \
    f32x4 s0_ = aq_[0], s1_ = aq_[1], s2_ = aq_[2], s3_ = aq_[3];             \
    float pv_[4];                                                             \
    _Pragma("unroll")                                                         \
    for (int q = 0; q < 4; ++q) {                                             \
        f32x4 acc = s0_ * tE[q][0];                                           \
        acc = s1_ * tE[q][1] + acc;                                           \
        acc = s2_ * tE[q][2] + acc;                                           \
        acc = s3_ * tE[q][3] + acc;                                           \
        float S_ = (acc.x + acc.y) + (acc.z + acc.w);                         \
        S_ += dppf<0xB1>(S_);                                                 \
        S_ += dppf<0x4E>(S_);                                                 \
        S_ += dppf<0x141>(S_);                                                \
        const float e_ = (q == 0) ? e4_.x : (q == 1) ? e4_.y                  \
                        : (q == 2) ? e4_.z : e4_.w;                           \
        const float al_ = e_ + Rcons_ + __logf(S_);                           \
        aa[q] = al_;                                                          \
        pv_[q] = __expf(al_ - Rpub_);                                         \
    }                                                                         \
    if (ig == 0) {                                                            \
        f32x4 pp_ = {pv_[0], pv_[1], pv_[2], pv_[3]};                         \
        *(f32x4*)(stateLDS + nxt_ * SPITCH + PI(j0)) = pp_;                   \
    }                                                                         \
    if (tid == 0) ringLDS[tt_ & 3] = aa[0];                                   \
    BAR();                                                                    \
}

// ---------------- main kernel: 256 blocks. role 0 = viterbi, role 1 = forward+num.
// 256 threads = 4 waves. wave w owns j in [32w, 32w+32).
// lane: ig = lane&7 -> i-range [16ig, 16ig+16); jd = lane>>3 -> j0 = w*32+jd*4.
__attribute__((amdgpu_flat_work_group_size(256, 256)))
__attribute__((amdgpu_waves_per_eu(1, 1)))
__global__ void crf_mainX(const float* __restrict__ logit,
                          const int* __restrict__ seq_lens,
                          const float* __restrict__ trans,
                          const float* __restrict__ startT,
                          const float* __restrict__ endT,
                          const int* __restrict__ target,
                          uint8_t* __restrict__ histG,
                          float* __restrict__ scr_logZ,
                          int* __restrict__ scr_last,
                          float* __restrict__ scr_num)
{
    extern __shared__ float smem[];
    float* transLDS = smem;                          // 16512
    float* stateLDS = smem + 16512;                  // 320 (2 * SPITCH)
    float* ringLDS  = smem + 16832;                  // 4
    float* redLDS   = smem + 16836;                  // 8
    int*   redILDS  = (int*)(smem + 16844);          // 4
    float* sumLDS   = smem + 16848;                  // 4
    float* eLDS     = smem + 16852;                  // 2 * CHK*TT = 8192
    uint8_t* hsLDS  = (uint8_t*)(smem + 25044);      // CHK*TT = 4096 B

    const int bid  = blockIdx.x;
    const int role = bid >> 7;
    const int b    = bid & (BB - 1);
    const int tid  = threadIdx.x;
    const int w    = tid >> 6;
    const int lane = tid & 63;
    const int ig   = lane & 7;
    const int jd   = lane >> 3;
    const int j0   = w * 32 + jd * 4;
    const int ibase = ig * 16;
    const int L = seq_lens[b];
    const size_t lbase = (size_t)b * (SS * TT);

    f32x4 ec[4];

    // prologue: stage chunk0 (rows [1, 1+CHK)) into eLDS buf0
    ECHUNK_LOAD(1);
    ECHUNK_STORE(eLDS);

    // stage transitions into padded LDS (stride TRP)
    for (int m = tid; m < TT * TT; m += 256)
        transLDS[(m >> 7) * TRP + (m & 127)] = trans[m];
    __syncthreads();   // full drain: echunk0 + trans staged

    // init alpha0 quad
    const f32x4 st4 = *(const f32x4*)(startT + j0);
    const f32x4 l04 = *(const f32x4*)(logit + lbase + j0);
    const f32x4 a04 = st4 + l04;

    if (role == 0) {
        // =================== VITERBI ===================
        f32x4 tj[4][4];  // T[ibase+4c+s][j0+q], pinned in VGPRs
#pragma unroll
        for (int q = 0; q < 4; ++q)
#pragma unroll
            for (int c = 0; c < 4; ++c) {
                tj[q][c].x = transLDS[(ibase + c * 4 + 0) * TRP + (j0 + q)];
                tj[q][c].y = transLDS[(ibase + c * 4 + 1) * TRP + (j0 + q)];
                tj[q][c].z = transLDS[(ibase + c * 4 + 2) * TRP + (j0 + q)];
                tj[q][c].w = transLDS[(ibase + c * 4 + 3) * TRP + (j0 + q)];
                PIN(tj[q][c]);
            }
        if (ig == 0) *(f32x4*)(stateLDS + PI(j0)) = a04;
        __syncthreads();

        uint8_t* hb = histG + (size_t)b * (SS * TT);

        int c = 0;
        for (int tc = 1; tc < L; tc += CHK, ++c) {
            const int tend = (tc + CHK < L) ? tc + CHK : L;
            const int n = tend - tc;
            const float* ecur = eLDS + (c & 1) * (CHK * TT);
            const bool more = (tc + CHK) < L;
            if (more) ECHUNK_LOAD(tc + CHK);   // 32 steps of latency slack

            for (int s = 0; s + 1 < n; s += 2) { VSTEP5(s, 0); VSTEP5(s + 1, 1); }
            if (n & 1) { VSTEP5(n - 1, 0); }

            // flush staged hist rows [tc, tend) -- coalesced dwordx4
            {
                const int lr = tid >> 3, cq = (tid & 7) * 16;
                if (lr < n) {
                    uint4 v = *(const uint4*)(hsLDS + lr * TT + cq);
                    *(uint4*)(hb + (size_t)(tc + lr) * TT + cq) = v;
                }
            }
            if (more) ECHUNK_STORE(eLDS + ((c + 1) & 1) * (CHK * TT));
            BAR();   // hsLDS reusable, next e-chunk visible
        }

        // ---- last_tag = argmax_j(score + end), first-index ----
        const int fin = (L - 1) & 1;
        if (tid < 128) {
            float lv = stateLDS[fin * SPITCH + PI(tid)] + endT[tid];
            int li = tid;
#pragma unroll
            for (int off = 1; off < 64; off <<= 1) {
                float ov = __shfl_xor(lv, off);
                int oi = __shfl_xor(li, off);
                if (ov > lv || (ov == lv && oi < li)) { lv = ov; li = oi; }
            }
            if ((tid & 63) == 0) { redLDS[tid >> 6] = lv; redILDS[tid >> 6] = li; }
        }
        __syncthreads();
        if (tid == 0) {
            int lt = (redLDS[1] > redLDS[0] ||
                      (redLDS[1] == redLDS[0] && redILDS[1] < redILDS[0]))
                     ? redILDS[1] : redILDS[0];
            scr_last[b] = lt;
        }
        // ---- identity fill of hist rows [L, SS) ----
        const int colq = (tid & 7) * 16;
        const uint32_t w0 = 0x03020100u + 0x01010101u * (uint32_t)colq;
        const uint4 pat = make_uint4(w0, w0 + 0x04040404u, w0 + 0x08080808u, w0 + 0x0C0C0C0Cu);
        for (int t0 = L; t0 < SS; t0 += 32) {
            int tt = t0 + (tid >> 3);
            if (tt < SS) *(uint4*)(hb + (size_t)tt * TT + colq) = pat;
        }
    } else {
        // =================== FORWARD (logZ) ===================
        f32x4 tE[4][4];  // exp(T[ibase+4c+s][j0+q]), pinned
#pragma unroll
        for (int q = 0; q < 4; ++q)
#pragma unroll
            for (int c = 0; c < 4; ++c) {
                tE[q][c].x = __expf(transLDS[(ibase + c * 4 + 0) * TRP + (j0 + q)]);
                tE[q][c].y = __expf(transLDS[(ibase + c * 4 + 1) * TRP + (j0 + q)]);
                tE[q][c].z = __expf(transLDS[(ibase + c * 4 + 2) * TRP + (j0 + q)]);
                tE[q][c].w = __expf(transLDS[(ibase + c * 4 + 3) * TRP + (j0 + q)]);
                PIN(tE[q][c]);
            }
        const float R0 = startT[0] + logit[lbase];  // alpha0[0], uniform
        float aa[4] = {a04.x, a04.y, a04.z, a04.w};
        if (ig == 0) {
            f32x4 ex = {__expf(a04.x - R0), __expf(a04.y - R0),
                        __expf(a04.z - R0), __expf(a04.w - R0)};
            *(f32x4*)(stateLDS + PI(j0)) = ex;
        }
        if (tid < 4) ringLDS[tid] = R0;
        __syncthreads();

        int c = 0;
        for (int tc = 1; tc < L; tc += CHK, ++c) {
            const int tend = (tc + CHK < L) ? tc + CHK : L;
            const int n = tend - tc;
            const float* ecur = eLDS + (c & 1) * (CHK * TT);
            const bool more = (tc + CHK) < L;
            if (more) ECHUNK_LOAD(tc + CHK);

            for (int s = 0; s + 1 < n; s += 2) { FSTEP5(s, 0); FSTEP5(s + 1, 1); }
            if (n & 1) { FSTEP5(n - 1, 0); }

            if (more) ECHUNK_STORE(eLDS + ((c + 1) & 1) * (CHK * TT));
            BAR();
        }

        // ---- logZ epilogue (exact max) ----
        const int freeb = L & 1;   // unused state buffer
        if (ig == 0) {
            f32x4 av = {aa[0], aa[1], aa[2], aa[3]};
            *(f32x4*)(stateLDS + freeb * SPITCH + PI(j0)) = av;
        }
        __syncthreads();
        float fval = -3.4e38f;
        if (tid < 128) fval = stateLDS[freeb * SPITCH + PI(tid)] + endT[tid];
        float tmx = fval;
#pragma unroll
        for (int off = 1; off < 64; off <<= 1) tmx = fmaxf(tmx, __shfl_xor(tmx, off));
        if ((tid & 63) == 0) redLDS[4 + (tid >> 6)] = tmx;
        __syncthreads();
        const float gm = fmaxf(redLDS[4], redLDS[5]);
        float se = (tid < 128) ? __expf(fval - gm) : 0.f;
#pragma unroll
        for (int off = 1; off < 64; off <<= 1) se += __shfl_xor(se, off);
        if ((tid & 63) == 0) sumLDS[tid >> 6] = se;
        __syncthreads();
        if (tid == 0)
            scr_logZ[b] = gm + __logf(sumLDS[0] + sumLDS[1] + sumLDS[2] + sumLDS[3]);
        __syncthreads();

        // ---- numerator (gold path score) ----
        float acc = 0.f;
        for (int tt = tid; tt < L; tt += 256) {
            int tg = target[b * SS + tt];
            acc += logit[((size_t)b * SS + tt) * TT + tg];
            if (tt >= 1) acc += trans[target[b * SS + tt - 1] * TT + tg];
        }
#pragma unroll
        for (int off = 1; off < 64; off <<= 1) acc += __shfl_xor(acc, off);
        if ((tid & 63) == 0) sumLDS[tid >> 6] = acc;
        __syncthreads();
        if (tid == 0) {
            float tot = sumLDS[0] + sumLDS[1] + sumLDS[2] + sumLDS[3];
            tot += startT[target[b * SS]] + endT[target[b * SS + L - 1]];
            scr_num[b] = tot;
        }
    }
}

// ---------------- phase 2: per-segment parallel backtrace of all 128 end-tags ----------------
__global__ void crf_btseg(uint8_t* __restrict__ histG)
{
    const int c = blockIdx.x;    // segment 0..31
    const int b = blockIdx.y;    // batch
    const int tid = threadIdx.x; // 128
    __shared__ __align__(16) uint8_t hl[SEGK * TT];

    const int lo = (c == 0) ? 1 : c * SEGK;
    const int nr = (c == 0) ? 63 : 64;
    const uint8_t* src = histG + (size_t)b * (SS * TT) + (size_t)lo * TT;
    for (int k = tid; k < (nr * TT) / 16; k += 128)
        ((uint4*)hl)[k] = ((const uint4*)src)[k];
    __syncthreads();

    int tau = tid;
    uint32_t w[16];
#pragma unroll
    for (int q = 0; q < 16; ++q) w[q] = 0u;
    if (c == 0) {
#pragma unroll
        for (int r = 62; r >= 0; --r) {
            tau = hl[r * TT + tau];
            w[r >> 2] |= ((uint32_t)tau) << ((r & 3) * 8);
        }
    } else {
#pragma unroll
        for (int r = 63; r >= 0; --r) {
            tau = hl[r * TT + tau];
            w[r >> 2] |= ((uint32_t)tau) << ((r & 3) * 8);
        }
    }
    uint4* dst = (uint4*)(histG + (size_t)b * (SS * TT) + (size_t)c * 8192 + (size_t)tid * 64);
    dst[0] = make_uint4(w[0], w[1], w[2], w[3]);
    dst[1] = make_uint4(w[4], w[5], w[6], w[7]);
    dst[2] = make_uint4(w[8], w[9], w[10], w[11]);
    dst[3] = make_uint4(w[12], w[13], w[14], w[15]);
}

// ---------------- phase 3: serial chain over 32 segment maps per batch ----------------
__global__ void crf_btchain(const uint8_t* __restrict__ histG,
                            const int* __restrict__ scr_last,
                            int* __restrict__ scr_bt,
                            float* __restrict__ out_pred)
{
    const int b = threadIdx.x;
    if (b >= BB) return;
    int tau = scr_last[b];
    out_pred[(size_t)b * SS + (SS - 1)] = (float)tau;
    for (int c = NSEG - 1; c >= 0; --c) {
        scr_bt[b * NSEG + c] = tau;
        tau = histG[(size_t)b * (SS * TT) + (size_t)c * 8192 + (size_t)tau * 64];
    }
}

// ---------------- phase 4: parallel fill of pred from chosen paths ----------------
__global__ void crf_btfill(const uint8_t* __restrict__ histG,
                           const int* __restrict__ scr_bt,
                           float* __restrict__ out_pred)
{
    const int c = blockIdx.x;
    const int b = blockIdx.y;
    const int s = threadIdx.x;   // 64
    if (c == 0 && s > 62) return;
    const int js = scr_bt[b * NSEG + c];
    uint8_t v = histG[(size_t)b * (SS * TT) + (size_t)c * 8192 + (size_t)js * 64 + s];
    const int pos = (c == 0) ? s : (c * SEGK - 1 + s);
    out_pred[(size_t)b * SS + pos] = (float)v;
}

// ---------------- loss = mean(logZ - num) ----------------
__global__ void crf_loss(const float* __restrict__ scr_logZ, const float* __restrict__ scr_num,
                         float* __restrict__ out)
{
    const int tid = threadIdx.x; // 128
    __shared__ float p2[2];
    float v = (tid < BB) ? (scr_logZ[tid] - scr_num[tid]) : 0.0f;
#pragma unroll
    for (int off = 1; off < 64; off <<= 1) v += __shfl_xor(v, off);
    if ((tid & 63) == 0) p2[tid >> 6] = v;
    __syncthreads();
    if (tid == 0) out[0] = (p2[0] + p2[1]) / (float)BB;
}

// ---------------- log_probs: swap + log_softmax, one wave per row ----------------
__global__ void crf_logprobs(const float* __restrict__ logit,
                             const float* __restrict__ predF,
                             float* __restrict__ outLP)
{
    const int wid = threadIdx.x >> 6;
    const int lane = threadIdx.x & 63;
    const size_t row = (size_t)blockIdx.x * 4 + wid;
    const float2* rp = (const float2*)(logit + row * TT);
    float2 v = rp[lane];
    const int pred = (int)predF[row];

    float mv; int mi;
    if (v.y > v.x) { mv = v.y; mi = lane * 2 + 1; }
    else           { mv = v.x; mi = lane * 2; }
#pragma unroll
    for (int off = 1; off < 64; off <<= 1) {
        float ov = __shfl_xor(mv, off);
        int oi = __shfl_xor(mi, off);
        if (ov > mv || (ov == mv && oi < mi)) { mv = ov; mi = oi; }
    }
    float se = __expf(v.x - mv) + __expf(v.y - mv);
#pragma unroll
    for (int off = 1; off < 64; off <<= 1) se += __shfl_xor(se, off);
    const float lse = __logf(se);

    float px = __shfl(v.x, pred >> 1);
    float py = __shfl(v.y, pred >> 1);
    float vp = (pred & 1) ? py : px;

    float ox = (lane * 2 == pred) ? mv : ((lane * 2 == mi) ? vp : v.x);
    float oy = (lane * 2 + 1 == pred) ? mv : ((lane * 2 + 1 == mi) ? vp : v.y);
    float* op = outLP + row * TT + lane * 2;
    op[0] = (ox - mv) - lse;
    op[1] = (oy - mv) - lse;
}

extern "C" void kernel_launch(void* const* d_in, const int* in_sizes, int n_in,
                              void* d_out, int out_size, void* d_ws, size_t ws_size,
                              hipStream_t stream)
{
    const float* logit    = (const float*)d_in[0];
    const int*   target   = (const int*)d_in[1];
    const int*   seq_lens = (const int*)d_in[2];
    const float* trans    = (const float*)d_in[3];
    const float* startT   = (const float*)d_in[4];
    const float* endT     = (const float*)d_in[5];

    float* out      = (float*)d_out;
    float* out_pred = out + 1;
    float* outLP    = out + 1 + (size_t)BB * SS;                 // 262145
    uint8_t* histG  = (uint8_t*)(out + 262148);                  // 16B-aligned, 33.5MB
    float* scr      = out + ((size_t)1 + (size_t)BB * SS + (size_t)BB * SS * TT - 4480);
    float* scr_logZ = scr;                // 128
    float* scr_num  = scr + 128;          // 128
    int*   scr_last = (int*)(scr + 256);  // 128
    int*   scr_bt   = (int*)(scr + 384);  // 128*32

    const int dynLDS = (25044 + 1024) * 4;  // 104272 B
    hipFuncSetAttribute((const void*)crf_mainX,
                        hipFuncAttributeMaxDynamicSharedMemorySize, dynLDS);

    crf_mainX<<<2 * BB, 256, dynLDS, stream>>>(logit, seq_lens, trans, startT, endT,
                                               target, histG, scr_logZ, scr_last, scr_num);
    crf_btseg<<<dim3(NSEG, BB), 128, 0, stream>>>(histG);
    crf_btchain<<<1, 128, 0, stream>>>(histG, scr_last, scr_bt, out_pred);
    crf_btfill<<<dim3(NSEG, BB), 64, 0, stream>>>(histG, scr_bt, out_pred);
    crf_loss<<<1, 128, 0, stream>>>(scr_logZ, scr_num, out);
    crf_logprobs<<<(BB * SS) / 4, 256, 0, stream>>>(logit, out_pred, outLP);
}

// Round 9
// 1572.721 us; speedup vs baseline: 1.1012x; 1.1012x over previous
//
#include <hip/hip_runtime.h>
#include <stdint.h>

#define BB 128
#define SS 2048
#define TT 128
#define NSEG 32
#define SEGK 64

// padded layouts (bank-conflict-free, validated R4)
#define TRP 129              // trans row stride (129 % 32 == 1)
#define VSTRIDE 136          // state buffer stride
#define H1OFF 68             // half-1 offset (68 % 32 == 4 -> disjoint banks vs half-0)

typedef float f32x4 __attribute__((ext_vector_type(4)));

// raw barrier: drain LDS ops only (NOT vmcnt -> prefetch loads stay in flight)
#define BAR() asm volatile("s_waitcnt lgkmcnt(0)\n\ts_barrier" ::: "memory")
#define PIN(x) asm volatile("" : "+v"(x))

__device__ __forceinline__ float dpp_swap1_f(float x) {
    int i = __float_as_int(x);
    i = __builtin_amdgcn_update_dpp(0, i, 0xB1, 0xF, 0xF, true);
    return __int_as_float(i);
}
__device__ __forceinline__ int dpp_swap1_i(int x) {
    return __builtin_amdgcn_update_dpp(0, x, 0xB1, 0xF, 0xF, true);
}

__device__ __forceinline__ f32x4 fmax4v(f32x4 a, f32x4 b) {
    f32x4 r;
    r.x = fmaxf(a.x, b.x); r.y = fmaxf(a.y, b.y);
    r.z = fmaxf(a.z, b.z); r.w = fmaxf(a.w, b.w);
    return r;
}

#define CLAMPROW(k) (((k) < L) ? (k) : (L - 1))

// one viterbi step: single LDS round-trip; argmax rescan fully in registers.
#define VSTEP(tt, CURP, EREG)                                                 \
{                                                                             \
    const int cur_ = (CURP), nxt_ = 1 - cur_;                                 \
    const float e_ = EREG;                                                    \
    EREG = logit[lbase + (size_t)CLAMPROW((tt) + 4) * TT + j];                \
    const f32x4* sq_ = (const f32x4*)(vecLDS + cur_ * VSTRIDE + h * H1OFF);   \
    f32x4 Q[16];                                                              \
    _Pragma("unroll")                                                         \
    for (int c = 0; c < 16; ++c) {                                            \
        f32x4 P_ = sq_[c] + tC[c];   /* s + t  (exact) */                     \
        Q[c] = P_ + e_;              /* (s+t)+e (exact reference order) */    \
    }                                                                         \
    float cm_[8];                                                             \
    _Pragma("unroll")                                                         \
    for (int cc = 0; cc < 8; ++cc) {                                          \
        f32x4 m4 = fmax4v(Q[2 * cc], Q[2 * cc + 1]);                          \
        cm_[cc] = fmaxf(fmaxf(m4.x, m4.y), fmaxf(m4.z, m4.w));                \
    }                                                                         \
    float M_ = fmaxf(fmaxf(fmaxf(cm_[0], cm_[1]), fmaxf(cm_[2], cm_[3])),     \
                     fmaxf(fmaxf(cm_[4], cm_[5]), fmaxf(cm_[6], cm_[7])));    \
    const float v_ = fmaxf(M_, dpp_swap1_f(M_));  /* global max value */      \
    /* first chunk (this half) holding v_; if none, selected chunk has all    \
       Q < v_ so no compare fires and idx stays INF */                        \
    int cwin_ = 7;                                                            \
    _Pragma("unroll")                                                         \
    for (int cc = 6; cc >= 0; --cc) cwin_ = (cm_[cc] == v_) ? cc : cwin_;     \
    /* branchless 3-level select of chunk cwin_'s two f32x4 (no dyn index) */ \
    const bool b2_ = (cwin_ & 4) != 0;                                        \
    f32x4 A0 = b2_ ? Q[8]  : Q[0], B0 = b2_ ? Q[9]  : Q[1];                   \
    f32x4 A1 = b2_ ? Q[10] : Q[2], B1 = b2_ ? Q[11] : Q[3];                   \
    f32x4 A2 = b2_ ? Q[12] : Q[4], B2 = b2_ ? Q[13] : Q[5];                   \
    f32x4 A3 = b2_ ? Q[14] : Q[6], B3 = b2_ ? Q[15] : Q[7];                   \
    const bool b1_ = (cwin_ & 2) != 0;                                        \
    f32x4 C0 = b1_ ? A2 : A0, D0 = b1_ ? B2 : B0;                             \
    f32x4 C1 = b1_ ? A3 : A1, D1 = b1_ ? B3 : B1;                             \
    const bool b0_ = (cwin_ & 1) != 0;                                        \
    f32x4 QA = b0_ ? C1 : C0, QB = b0_ ? D1 : D0;                             \
    const int kb_ = ibase0 + cwin_ * 8;                                       \
    int idx_ = 0x7fffffff;                                                    \
    idx_ = (QB.w == v_) ? kb_ + 7 : idx_;                                     \
    idx_ = (QB.z == v_) ? kb_ + 6 : idx_;                                     \
    idx_ = (QB.y == v_) ? kb_ + 5 : idx_;                                     \
    idx_ = (QB.x == v_) ? kb_ + 4 : idx_;                                     \
    idx_ = (QA.w == v_) ? kb_ + 3 : idx_;                                     \
    idx_ = (QA.z == v_) ? kb_ + 2 : idx_;                                     \
    idx_ = (QA.y == v_) ? kb_ + 1 : idx_;                                     \
    idx_ = (QA.x == v_) ? kb_ + 0 : idx_;                                     \
    const int oidx_ = dpp_swap1_i(idx_);                                      \
    idx_ = (oidx_ < idx_) ? oidx_ : idx_;  /* first-index across halves */    \
    if (h == 0) {                                                             \
        vecLDS[nxt_ * VSTRIDE + joff] = v_;                                   \
        hb[(size_t)(tt) * TT + j] = (uint8_t)idx_;                            \
    }                                                                         \
    BAR();                                                                    \
}

// one forward step (R6-validated)
#define FSTEP(tt, CURP, EREG)                                                 \
{                                                                             \
    const int cur_ = (CURP), nxt_ = 1 - cur_;                                 \
    const float Rcons_ = ringLDS[((tt) - 3) & 3];                             \
    const float Rpub_  = ringLDS[((tt) - 2) & 3];                             \
    const float e_ = EREG;                                                    \
    EREG = logit[lbase + (size_t)CLAMPROW((tt) + 4) * TT + j];                \
    const f32x4* aq_ = (const f32x4*)(vecLDS + cur_ * VSTRIDE + h * H1OFF);   \
    f32x4 s4_ = {0.f, 0.f, 0.f, 0.f}, s4b_ = {0.f, 0.f, 0.f, 0.f};            \
    _Pragma("unroll")                                                         \
    for (int c = 0; c < 16; c += 2) {                                         \
        s4_  = aq_[c] * tE[c] + s4_;                                          \
        s4b_ = aq_[c + 1] * tE[c + 1] + s4b_;                                 \
    }                                                                         \
    f32x4 st_ = s4_ + s4b_;                                                   \
    float Ssum_ = (st_.x + st_.y) + (st_.z + st_.w);                          \
    Ssum_ += dpp_swap1_f(Ssum_);                                              \
    alpha = e_ + Rcons_ + __logf(Ssum_);                                      \
    const float p_ = __expf(alpha - Rpub_);                                   \
    if (h == 0) vecLDS[nxt_ * VSTRIDE + joff] = p_;                           \
    if (tid == 0) ringLDS[(tt) & 3] = alpha;                                  \
    BAR();                                                                    \
}

// ---------------- main kernel: 256 blocks. role 0 = viterbi, role 1 = forward+num.
// 256 threads: j=tid>>1, h=tid&1 owns i-half [64h,64h+64). ----------------
__attribute__((amdgpu_flat_work_group_size(256, 256)))
__attribute__((amdgpu_waves_per_eu(1, 1)))
__global__ void crf_mainX(const float* __restrict__ logit,
                          const int* __restrict__ seq_lens,
                          const float* __restrict__ trans,
                          const float* __restrict__ startT,
                          const float* __restrict__ endT,
                          const int* __restrict__ target,
                          uint8_t* __restrict__ histG,
                          float* __restrict__ scr_logZ,
                          int* __restrict__ scr_last,
                          float* __restrict__ scr_num)
{
    extern __shared__ float smem[];
    float* transLDS = smem;                         // 16512 floats
    float* vecLDS   = smem + 16512;                 // 2 * VSTRIDE = 272
    float* ringLDS  = smem + 16512 + 272;           // 4
    float* redLDS   = smem + 16512 + 276;           // 8
    int*   redILDS  = (int*)(smem + 16512 + 284);   // 4
    float* sumLDS   = smem + 16512 + 288;           // 4

    const int bid = blockIdx.x;
    const int role = bid >> 7;
    const int b = bid & (BB - 1);
    const int tid = threadIdx.x;
    const int j = tid >> 1;
    const int h = tid & 1;
    const int ibase0 = h << 6;
    const int joff = j + ((j >= 64) ? (H1OFF - 64) : 0);
    const int L = seq_lens[b];
    const size_t lbase = (size_t)b * (SS * TT);

    // stage transitions into padded LDS (stride TRP)
    for (int m = tid; m < TT * TT; m += 256)
        transLDS[(m >> 7) * TRP + (m & 127)] = trans[m];
    __syncthreads();

    // 4-deep rotating prefetch registers (rows 1..4, clamped)
    float e_a = logit[lbase + (size_t)CLAMPROW(1) * TT + j];
    float e_b = logit[lbase + (size_t)CLAMPROW(2) * TT + j];
    float e_c = logit[lbase + (size_t)CLAMPROW(3) * TT + j];
    float e_d = logit[lbase + (size_t)CLAMPROW(4) * TT + j];

    if (role == 0) {
        // =================== VITERBI ===================
        f32x4 tC[16];  // trans[i][j] for my i-half, pinned in VGPRs
#pragma unroll
        for (int c = 0; c < 16; ++c) {
            tC[c].x = transLDS[(ibase0 + c * 4 + 0) * TRP + j];
            tC[c].y = transLDS[(ibase0 + c * 4 + 1) * TRP + j];
            tC[c].z = transLDS[(ibase0 + c * 4 + 2) * TRP + j];
            tC[c].w = transLDS[(ibase0 + c * 4 + 3) * TRP + j];
            PIN(tC[c]);
        }
        const float a0 = startT[j] + logit[lbase + j];
        if (h == 0) vecLDS[joff] = a0;
        __syncthreads();

        uint8_t* hb = histG + (size_t)b * (SS * TT);

        // steady state: 4 steps/iteration, static parity (t starts at 1, step 4)
        int t = 1;
        for (; t + 3 < L; t += 4) {
            VSTEP(t + 0, 0, e_a);
            VSTEP(t + 1, 1, e_b);
            VSTEP(t + 2, 0, e_c);
            VSTEP(t + 3, 1, e_d);
        }
        for (; t < L; ++t) {
            VSTEP(t, ((t - 1) & 1), e_a);
            e_a = e_b; e_b = e_c; e_c = e_d;
        }

        // ---- last_tag = argmax_j(score + end), first-index ----
        const int fin = (L - 1) & 1;
        if (tid < 128) {
            const int toff = tid + ((tid >= 64) ? (H1OFF - 64) : 0);
            float lv = vecLDS[fin * VSTRIDE + toff] + endT[tid];
            int li = tid;
#pragma unroll
            for (int off = 1; off < 64; off <<= 1) {
                float ov = __shfl_xor(lv, off);
                int oi = __shfl_xor(li, off);
                if (ov > lv || (ov == lv && oi < li)) { lv = ov; li = oi; }
            }
            if ((tid & 63) == 0) { redLDS[tid >> 6] = lv; redILDS[tid >> 6] = li; }
        }
        __syncthreads();
        if (tid == 0) {
            int lt = (redLDS[1] > redLDS[0] ||
                      (redLDS[1] == redLDS[0] && redILDS[1] < redILDS[0]))
                     ? redILDS[1] : redILDS[0];
            scr_last[b] = lt;
        }
        // ---- identity fill of hist rows [L, SS) ----
        const int colq = (tid & 7) * 16;
        const uint32_t w0 = 0x03020100u + 0x01010101u * (uint32_t)colq;
        const uint4 pat = make_uint4(w0, w0 + 0x04040404u, w0 + 0x08080808u, w0 + 0x0C0C0C0Cu);
        for (int t0 = L; t0 < SS; t0 += 32) {
            int tt = t0 + (tid >> 3);
            if (tt < SS) *(uint4*)(hb + (size_t)tt * TT + colq) = pat;
        }
    } else {
        // =================== FORWARD (logZ) ===================
        f32x4 tE[16];  // exp(trans[i][j]), pinned
#pragma unroll
        for (int c = 0; c < 16; ++c) {
            tE[c].x = __expf(transLDS[(ibase0 + c * 4 + 0) * TRP + j]);
            tE[c].y = __expf(transLDS[(ibase0 + c * 4 + 1) * TRP + j]);
            tE[c].z = __expf(transLDS[(ibase0 + c * 4 + 2) * TRP + j]);
            tE[c].w = __expf(transLDS[(ibase0 + c * 4 + 3) * TRP + j]);
            PIN(tE[c]);
        }
        const float a0 = startT[j] + logit[lbase + j];
        const float R0 = startT[0] + logit[lbase + 0];  // alpha0[0], uniform
        float alpha = a0;
        if (h == 0) vecLDS[joff] = __expf(a0 - R0);
        if (tid < 4) ringLDS[tid] = R0;
        __syncthreads();

        int t = 1;
        for (; t + 3 < L; t += 4) {
            FSTEP(t + 0, 0, e_a);
            FSTEP(t + 1, 1, e_b);
            FSTEP(t + 2, 0, e_c);
            FSTEP(t + 3, 1, e_d);
        }
        for (; t < L; ++t) {
            FSTEP(t, ((t - 1) & 1), e_a);
            e_a = e_b; e_b = e_c; e_c = e_d;
        }

        // ---- logZ epilogue (exact max) ----
        const float fval = alpha + endT[j];
        float tmx = fval;
#pragma unroll
        for (int off = 1; off < 64; off <<= 1) tmx = fmaxf(tmx, __shfl_xor(tmx, off));
        if ((tid & 63) == 0) redLDS[4 + (tid >> 6)] = tmx;
        __syncthreads();
        const float gm = fmaxf(fmaxf(redLDS[4], redLDS[5]), fmaxf(redLDS[6], redLDS[7]));
        float se = (h == 0) ? __expf(fval - gm) : 0.f;
#pragma unroll
        for (int off = 1; off < 64; off <<= 1) se += __shfl_xor(se, off);
        if ((tid & 63) == 0) sumLDS[tid >> 6] = se;
        __syncthreads();
        if (tid == 0)
            scr_logZ[b] = gm + __logf(sumLDS[0] + sumLDS[1] + sumLDS[2] + sumLDS[3]);
        __syncthreads();

        // ---- numerator (gold path score) ----
        float acc = 0.f;
        for (int tt = tid; tt < L; tt += 256) {
            int tg = target[b * SS + tt];
            acc += logit[((size_t)b * SS + tt) * TT + tg];
            if (tt >= 1) acc += trans[target[b * SS + tt - 1] * TT + tg];
        }
#pragma unroll
        for (int off = 1; off < 64; off <<= 1) acc += __shfl_xor(acc, off);
        if ((tid & 63) == 0) sumLDS[tid >> 6] = acc;
        __syncthreads();
        if (tid == 0) {
            float tot = sumLDS[0] + sumLDS[1] + sumLDS[2] + sumLDS[3];
            tot += startT[target[b * SS]] + endT[target[b * SS + L - 1]];
            scr_num[b] = tot;
        }
    }
}

// ---------------- phase 2: per-segment parallel backtrace of all 128 end-tags ----------------
__global__ void crf_btseg(uint8_t* __restrict__ histG)
{
    const int c = blockIdx.x;    // segment 0..31
    const int b = blockIdx.y;    // batch
    const int tid = threadIdx.x; // 128
    __shared__ __align__(16) uint8_t hl[SEGK * TT];

    const int lo = (c == 0) ? 1 : c * SEGK;
    const int nr = (c == 0) ? 63 : 64;
    const uint8_t* src = histG + (size_t)b * (SS * TT) + (size_t)lo * TT;
    for (int k = tid; k < (nr * TT) / 16; k += 128)
        ((uint4*)hl)[k] = ((const uint4*)src)[k];
    __syncthreads();

    int tau = tid;
    uint32_t w[16];
#pragma unroll
    for (int q = 0; q < 16; ++q) w[q] = 0u;
    if (c == 0) {
#pragma unroll
        for (int r = 62; r >= 0; --r) {
            tau = hl[r * TT + tau];
            w[r >> 2] |= ((uint32_t)tau) << ((r & 3) * 8);
        }
    } else {
#pragma unroll
        for (int r = 63; r >= 0; --r) {
            tau = hl[r * TT + tau];
            w[r >> 2] |= ((uint32_t)tau) << ((r & 3) * 8);
        }
    }
    uint4* dst = (uint4*)(histG + (size_t)b * (SS * TT) + (size_t)c * 8192 + (size_t)tid * 64);
    dst[0] = make_uint4(w[0], w[1], w[2], w[3]);
    dst[1] = make_uint4(w[4], w[5], w[6], w[7]);
    dst[2] = make_uint4(w[8], w[9], w[10], w[11]);
    dst[3] = make_uint4(w[12], w[13], w[14], w[15]);
}

// ---------------- phase 3: serial chain over 32 segment maps per batch ----------------
__global__ void crf_btchain(const uint8_t* __restrict__ histG,
                            const int* __restrict__ scr_last,
                            int* __restrict__ scr_bt,
                            float* __restrict__ out_pred)
{
    const int b = threadIdx.x;
    if (b >= BB) return;
    int tau = scr_last[b];
    out_pred[(size_t)b * SS + (SS - 1)] = (float)tau;
    for (int c = NSEG - 1; c >= 0; --c) {
        scr_bt[b * NSEG + c] = tau;
        tau = histG[(size_t)b * (SS * TT) + (size_t)c * 8192 + (size_t)tau * 64];
    }
}

// ---------------- phase 4: parallel fill of pred from chosen paths ----------------
__global__ void crf_btfill(const uint8_t* __restrict__ histG,
                           const int* __restrict__ scr_bt,
                           float* __restrict__ out_pred)
{
    const int c = blockIdx.x;
    const int b = blockIdx.y;
    const int s = threadIdx.x;   // 64
    if (c == 0 && s > 62) return;
    const int js = scr_bt[b * NSEG + c];
    uint8_t v = histG[(size_t)b * (SS * TT) + (size_t)c * 8192 + (size_t)js * 64 + s];
    const int pos = (c == 0) ? s : (c * SEGK - 1 + s);
    out_pred[(size_t)b * SS + pos] = (float)v;
}

// ---------------- loss = mean(logZ - num) ----------------
__global__ void crf_loss(const float* __restrict__ scr_logZ, const float* __restrict__ scr_num,
                         float* __restrict__ out)
{
    const int tid = threadIdx.x; // 128
    __shared__ float p2[2];
    float v = (tid < BB) ? (scr_logZ[tid] - scr_num[tid]) : 0.0f;
#pragma unroll
    for (int off = 1; off < 64; off <<= 1) v += __shfl_xor(v, off);
    if ((tid & 63) == 0) p2[tid >> 6] = v;
    __syncthreads();
    if (tid == 0) out[0] = (p2[0] + p2[1]) / (float)BB;
}

// ---------------- log_probs: swap + log_softmax, one wave per row ----------------
__global__ void crf_logprobs(const float* __restrict__ logit,
                             const float* __restrict__ predF,
                             float* __restrict__ outLP)
{
    const int wid = threadIdx.x >> 6;
    const int lane = threadIdx.x & 63;
    const size_t row = (size_t)blockIdx.x * 4 + wid;
    const float2* rp = (const float2*)(logit + row * TT);
    float2 v = rp[lane];
    const int pred = (int)predF[row];

    float mv; int mi;
    if (v.y > v.x) { mv = v.y; mi = lane * 2 + 1; }
    else           { mv = v.x; mi = lane * 2; }
#pragma unroll
    for (int off = 1; off < 64; off <<= 1) {
        float ov = __shfl_xor(mv, off);
        int oi = __shfl_xor(mi, off);
        if (ov > mv || (ov == mv && oi < mi)) { mv = ov; mi = oi; }
    }
    float se = __expf(v.x - mv) + __expf(v.y - mv);
#pragma unroll
    for (int off = 1; off < 64; off <<= 1) se += __shfl_xor(se, off);
    const float lse = __logf(se);

    float px = __shfl(v.x, pred >> 1);
    float py = __shfl(v.y, pred >> 1);
    float vp = (pred & 1) ? py : px;

    float ox = (lane * 2 == pred) ? mv : ((lane * 2 == mi) ? vp : v.x);
    float oy = (lane * 2 + 1 == pred) ? mv : ((lane * 2 + 1 == mi) ? vp : v.y);
    float* op = outLP + row * TT + lane * 2;
    op[0] = (ox - mv) - lse;
    op[1] = (oy - mv) - lse;
}

extern "C" void kernel_launch(void* const* d_in, const int* in_sizes, int n_in,
                              void* d_out, int out_size, void* d_ws, size_t ws_size,
                              hipStream_t stream)
{
    const float* logit    = (const float*)d_in[0];
    const int*   target   = (const int*)d_in[1];
    const int*   seq_lens = (const int*)d_in[2];
    const float* trans    = (const float*)d_in[3];
    const float* startT   = (const float*)d_in[4];
    const float* endT     = (const float*)d_in[5];

    float* out      = (float*)d_out;
    float* out_pred = out + 1;
    float* outLP    = out + 1 + (size_t)BB * SS;                 // 262145
    uint8_t* histG  = (uint8_t*)(out + 262148);                  // 16B-aligned, 33.5MB
    float* scr      = out + ((size_t)1 + (size_t)BB * SS + (size_t)BB * SS * TT - 4480);
    float* scr_logZ = scr;                // 128
    float* scr_num  = scr + 128;          // 128
    int*   scr_last = (int*)(scr + 256);  // 128
    int*   scr_bt   = (int*)(scr + 384);  // 128*32

    const int dynLDS = (16512 + 292) * 4;  // ~67.2KB
    hipFuncSetAttribute((const void*)crf_mainX,
                        hipFuncAttributeMaxDynamicSharedMemorySize, dynLDS);

    crf_mainX<<<2 * BB, 256, dynLDS, stream>>>(logit, seq_lens, trans, startT, endT,
                                               target, histG, scr_logZ, scr_last, scr_num);
    crf_btseg<<<dim3(NSEG, BB), 128, 0, stream>>>(histG);
    crf_btchain<<<1, 128, 0, stream>>>(histG, scr_last, scr_bt, out_pred);
    crf_btfill<<<dim3(NSEG, BB), 64, 0, stream>>>(histG, scr_bt, out_pred);
    crf_loss<<<1, 128, 0, stream>>>(scr_logZ, scr_num, out);
    crf_logprobs<<<(BB * SS) / 4, 256, 0, stream>>>(logit, out_pred, outLP);
}